// Round 9
// baseline (183.870 us; speedup 1.0000x reference)
//
#include <hip/hip_runtime.h>
#include <math.h>

#define EPS 1e-5f
#define MODC 352

__device__ __forceinline__ float silu_f(float x) {
    return x / (1.0f + expf(-x));
}

// One MLP stage: out[8 rows x 64 cols] = act(in[8 rows, K] @ w[K x NC] + bias).
// 1024 threads = 64 cols x KS=16 k-slices. Each thread: 8 rows x 1 col,
// KC = K/16 (<=32) serial k, unroll-4 -> 16 independent scalar w loads in
// flight + 8 accumulator chains. Split-k partials reduced via LDS.
// Grid: (rows/8, ceil(NC/64)) -> 768-1024 blocks, 2 blocks/CU, 32 waves/CU.
template <int K, int NC, bool EMB_IN, bool POST_SILU>
__global__ __launch_bounds__(1024) void k_stage(
    const float* __restrict__ in,    // [M][K]  (unused if EMB_IN)
    const float* __restrict__ t,     // [M]     (EMB_IN only)
    const float* __restrict__ w,     // [K][NC]
    const float* __restrict__ bias,  // [NC]
    float* __restrict__ out)         // [M][NC]
{
    constexpr int KS = 16, KC = K / KS;  // K=256 -> 16, K=512 -> 32
    constexpr int C = 64;

    __shared__ __align__(16) float s_in[8][K];        // 8 or 16 KB
    __shared__ __align__(16) float s_acc[KS][8][C];   // 32 KB

    int tid = threadIdx.x;
    int row0 = blockIdx.x * 8;
    int col0 = blockIdx.y * C;

    if constexpr (EMB_IN) {
        // timestep embedding into s_in: emb[j] = j<128 ? cos(t*f_j) : sin(t*f_{j-128})
        const float lm = 9.210340371976184f;   // ln(10000)
        for (int idx = tid; idx < 8 * K; idx += 1024) {
            int r = idx / K, j = idx - r * K;
            int h = j & 127;
            float freq = expf(-lm * (float)h * (1.0f / 128.0f));
            float arg = t[row0 + r] * freq;
            s_in[r][j] = (j < 128) ? cosf(arg) : sinf(arg);
        }
    } else {
        for (int idx = tid; idx < 8 * (K / 4); idx += 1024) {
            int r = idx / (K / 4), k4 = idx - r * (K / 4);
            *(float4*)&s_in[r][k4 * 4] =
                *(const float4*)(in + (size_t)(row0 + r) * K + k4 * 4);
        }
    }
    __syncthreads();

    int c  = tid & 63;
    int ks = tid >> 6;                     // wave-uniform k-slice (0..15)
    int j  = col0 + c;
    int jj = (j < NC) ? j : (NC - 1);      // clamp tail cols (garbage, never stored)
    const float* wp = w + jj;

    float acc[8] = {0, 0, 0, 0, 0, 0, 0, 0};
    int kbeg = ks * KC;

#pragma unroll 4
    for (int k0 = kbeg; k0 < kbeg + KC; k0 += 4) {
        float wv[4];
#pragma unroll
        for (int u = 0; u < 4; ++u) wv[u] = wp[(size_t)(k0 + u) * NC];
        float4 sa[8];
#pragma unroll
        for (int r = 0; r < 8; ++r) sa[r] = *(const float4*)&s_in[r][k0];
#pragma unroll
        for (int u = 0; u < 4; ++u)
#pragma unroll
            for (int r = 0; r < 8; ++r)
                acc[r] += ((const float*)&sa[r])[u] * wv[u];
    }

#pragma unroll
    for (int r = 0; r < 8; ++r) s_acc[ks][r][c] = acc[r];
    __syncthreads();

    // 512 outputs (8 rows x 64 cols), threads 0..511 take one each.
    if (tid < 512) {
        int r  = tid >> 6;
        int cc = tid & 63;
        int jo = col0 + cc;
        if (jo < NC) {
            float v = 0.f;
#pragma unroll
            for (int s = 0; s < KS; ++s) v += s_acc[s][r][cc];
            v += bias[jo];
            if (POST_SILU) v = silu_f(v);
            out[(size_t)(row0 + r) * NC + jo] = v;
        }
    }
}

// One wave (64 lanes) per node. Row = 480 f32 = 120 float4.
// float4 idx:  0..31 -> seg0 (layernorm, floats 0..127)
//             32..79 -> seg1 (floats 128..319, 192 elems)
//             80..119-> seg2 (floats 320..479, 160 elems)
__global__ __launch_bounds__(256) void k_main(const float* __restrict__ x,
                                              const int* __restrict__ batch,
                                              const float* __restrict__ mod,
                                              float* __restrict__ out, int N) {
    int node = blockIdx.x * 4 + (threadIdx.x >> 6);
    if (node >= N) return;
    int lane = threadIdx.x & 63;

    const float4* rp = (const float4*)(x + (size_t)node * 480);
    float4 a = rp[lane];                         // f4 idx lane (0..63)
    float4 c = make_float4(0.f, 0.f, 0.f, 0.f);
    if (lane < 56) c = rp[64 + lane];            // f4 idx 64..119

    float s0 = 0.f, q0 = 0.f, q1 = 0.f, q2 = 0.f;
    float da = a.x * a.x + a.y * a.y + a.z * a.z + a.w * a.w;
    if (lane < 32) { s0 = a.x + a.y + a.z + a.w; q0 = da; }
    else           { q1 = da; }
    float dc = c.x * c.x + c.y * c.y + c.z * c.z + c.w * c.w;
    if (lane < 16)      q1 += dc;
    else if (lane < 56) q2 = dc;

#pragma unroll
    for (int m = 1; m < 64; m <<= 1) {
        s0 += __shfl_xor(s0, m, 64);
        q0 += __shfl_xor(q0, m, 64);
        q1 += __shfl_xor(q1, m, 64);
        q2 += __shfl_xor(q2, m, 64);
    }

    int b = batch[node];
    const float* mrow = mod + (size_t)b * MODC;
    float4 m4 = *(const float4*)mrow;            // scales 0..2 (+unused)

    float mean = s0 * (1.0f / 128.0f);
    float var  = q0 * (1.0f / 128.0f) - mean * mean;
    float r0 = rsqrtf(var + EPS) * (1.0f + m4.x);
    float r1 = rsqrtf(q1 * (1.0f / 192.0f) + EPS) * (1.0f + m4.y);
    float r2 = rsqrtf(q2 * (1.0f / 160.0f) + EPS) * (1.0f + m4.z);

    float4* op = (float4*)(out + (size_t)node * 480);
    float4 o;
    if (lane < 32) {
        float4 sh = *(const float4*)(mrow + 224 + 4 * lane);   // shifts
        o.x = (a.x - mean) * r0 + sh.x;
        o.y = (a.y - mean) * r0 + sh.y;
        o.z = (a.z - mean) * r0 + sh.z;
        o.w = (a.w - mean) * r0 + sh.w;
    } else {
        o.x = a.x * r1; o.y = a.y * r1; o.z = a.z * r1; o.w = a.w * r1;
    }
    op[lane] = o;
    if (lane < 56) {
        float rr = (lane < 16) ? r1 : r2;
        float4 o2;
        o2.x = c.x * rr; o2.y = c.y * rr; o2.z = c.z * rr; o2.w = c.w * rr;
        op[64 + lane] = o2;
    }
}

extern "C" void kernel_launch(void* const* d_in, const int* in_sizes, int n_in,
                              void* d_out, int out_size, void* d_ws, size_t ws_size,
                              hipStream_t stream) {
    const float* node_input = (const float*)d_in[0];
    const float* t          = (const float*)d_in[1];
    const int*   batch      = (const int*)d_in[2];
    const float* w1         = (const float*)d_in[3];
    const float* b1         = (const float*)d_in[4];
    const float* w2         = (const float*)d_in[5];
    const float* b2         = (const float*)d_in[6];
    const float* wm         = (const float*)d_in[7];
    const float* bm         = (const float*)d_in[8];
    float* out = (float*)d_out;

    int N = in_sizes[0] / 480;   // 100000
    int B = in_sizes[1];         // 1024

    float* ws = (float*)d_ws;
    float* h1 = ws;                        // B*512: silu(emb@w1+b1)
    float* h2 = h1 + (size_t)B * 512;      // B*512: silu(h1@w2+b2)  (silu folded)
    float* mb = h2 + (size_t)B * 512;      // B*352: mod

    // stage 1: emb (in-kernel trig) @ w1 + b1, silu
    k_stage<256, 512, true,  true ><<<dim3(B / 8, 8), 1024, 0, stream>>>(
        nullptr, t, w1, b1, h1);
    // stage 2: h1 @ w2 + b2, trailing silu folded (next stage wants silu(t_emb))
    k_stage<512, 512, false, true ><<<dim3(B / 8, 8), 1024, 0, stream>>>(
        h1, nullptr, w2, b2, h2);
    // stage 3: h2 @ wm + bm  (full 352 cols)
    k_stage<512, 352, false, false><<<dim3(B / 8, 6), 1024, 0, stream>>>(
        h2, nullptr, wm, bm, mb);

    k_main<<<(N + 3) / 4, 256, 0, stream>>>(node_input, batch, mb, out, N);
}

// Round 10
// 115.470 us; speedup vs baseline: 1.5924x; 1.5924x over previous
//
#include <hip/hip_runtime.h>
#include <math.h>

#define EPS 1e-5f
#define MODW 132   // compact mod row: [0..3]=scale cols 0..3 (3 used), [4..131]=shift[0..127]

__device__ __forceinline__ float silu_f(float x) {
    return x / (1.0f + expf(-x));
}

// One MLP stage: out[8 rows x 64 cols] = act(in[8 rows, K] @ w[K x NC] + bias).
// 512 threads = 64 cols x KS=8 k-slices (wave-uniform). Each thread: 8 rows x
// 1 col. k-loop in chunks of 16: 16 independent scalar w loads issued as one
// batch (one waitcnt cluster, 4 KB/wave in flight), then 4x[8 LDS-broadcast
// reads + 32 FMAs]. Split-k partials reduced via LDS.
// COLMAP: compute only w cols {0..3} U [224,352) into compact 132-col rows.
// Grid: (rows/8, colgroups). 512 thr, ~32 KB LDS -> 4 blocks/CU.
template <int K, int NC, int OUTC, int OUTW, bool EMB_IN, bool POST_SILU, bool COLMAP>
__global__ __launch_bounds__(512) void k_stage(
    const float* __restrict__ in,    // [M][K]  (unused if EMB_IN)
    const float* __restrict__ t,     // [M]     (EMB_IN only)
    const float* __restrict__ w,     // [K][NC]
    const float* __restrict__ bias,  // [NC]
    float* __restrict__ out)         // [M][OUTW]
{
    constexpr int KS = 8, KC = K / KS;   // K=256 -> 32, K=512 -> 64
    constexpr int C = 64;

    __shared__ __align__(16) float s_in[8][K];        // 8 or 16 KB
    __shared__ __align__(16) float s_acc[KS][8][C];   // 16 KB

    int tid = threadIdx.x;
    int row0 = blockIdx.x * 8;
    int col0 = blockIdx.y * C;

    if constexpr (EMB_IN) {
        // timestep embedding into s_in: emb[j] = j<128 ? cos(t*f_j) : sin(t*f_{j-128})
        const float lm = 9.210340371976184f;   // ln(10000)
        for (int idx = tid; idx < 8 * K; idx += 512) {
            int r = idx / K, j = idx - r * K;
            int h = j & 127;
            float freq = expf(-lm * (float)h * (1.0f / 128.0f));
            float arg = t[row0 + r] * freq;
            s_in[r][j] = (j < 128) ? cosf(arg) : sinf(arg);
        }
    } else {
        for (int idx = tid; idx < 8 * (K / 4); idx += 512) {
            int r = idx / (K / 4), k4 = idx - r * (K / 4);
            *(float4*)&s_in[r][k4 * 4] =
                *(const float4*)(in + (size_t)(row0 + r) * K + k4 * 4);
        }
    }
    __syncthreads();

    int c  = tid & 63;
    int ks = tid >> 6;                     // wave-uniform k-slice (0..7)
    int oc = col0 + c;                     // output col
    int wcol;                              // col in w
    if constexpr (COLMAP) {
        int occ = (oc < OUTC) ? oc : (OUTC - 1);   // clamp (garbage, never stored)
        wcol = (occ < 4) ? occ : (220 + occ);      // {0..3} U [224,352)
    } else {
        wcol = (oc < NC) ? oc : (NC - 1);
    }
    const float* wp = w + wcol;

    float acc[8] = {0, 0, 0, 0, 0, 0, 0, 0};
    int kbeg = ks * KC;

#pragma unroll 1
    for (int k0 = kbeg; k0 < kbeg + KC; k0 += 16) {
        // 16 independent scalar w loads -> one batched waitcnt cluster
        float wv[16];
#pragma unroll
        for (int u = 0; u < 16; ++u) wv[u] = wp[(size_t)(k0 + u) * NC];
#pragma unroll
        for (int q = 0; q < 4; ++q) {
            float4 sa[8];
#pragma unroll
            for (int r = 0; r < 8; ++r) sa[r] = *(const float4*)&s_in[r][k0 + 4 * q];
#pragma unroll
            for (int u = 0; u < 4; ++u)
#pragma unroll
                for (int r = 0; r < 8; ++r)
                    acc[r] += ((const float*)&sa[r])[u] * wv[4 * q + u];
        }
    }

#pragma unroll
    for (int r = 0; r < 8; ++r) s_acc[ks][r][c] = acc[r];
    __syncthreads();

    // 512 outputs (8 rows x 64 cols), one per thread.
    {
        int r  = tid >> 6;
        int cc = tid & 63;
        int jo = col0 + cc;
        if (jo < OUTC) {
            int wc = COLMAP ? ((jo < 4) ? jo : (220 + jo)) : jo;
            float v = 0.f;
#pragma unroll
            for (int s = 0; s < KS; ++s) v += s_acc[s][r][cc];
            v += bias[wc];
            if (POST_SILU) v = silu_f(v);
            out[(size_t)(row0 + r) * OUTW + jo] = v;
        }
    }
}

// One wave (64 lanes) per node. Row = 480 f32 = 120 float4.
// float4 idx:  0..31 -> seg0 (layernorm, floats 0..127)
//             32..79 -> seg1 (floats 128..319, 192 elems)
//             80..119-> seg2 (floats 320..479, 160 elems)
// mod row is compact MODW=132: [0..2] scales, [4+i] = shift[i] (i<128).
__global__ __launch_bounds__(256) void k_main(const float* __restrict__ x,
                                              const int* __restrict__ batch,
                                              const float* __restrict__ mod,
                                              float* __restrict__ out, int N) {
    int node = blockIdx.x * 4 + (threadIdx.x >> 6);
    if (node >= N) return;
    int lane = threadIdx.x & 63;

    const float4* rp = (const float4*)(x + (size_t)node * 480);
    float4 a = rp[lane];                         // f4 idx lane (0..63)
    float4 c = make_float4(0.f, 0.f, 0.f, 0.f);
    if (lane < 56) c = rp[64 + lane];            // f4 idx 64..119

    float s0 = 0.f, q0 = 0.f, q1 = 0.f, q2 = 0.f;
    float da = a.x * a.x + a.y * a.y + a.z * a.z + a.w * a.w;
    if (lane < 32) { s0 = a.x + a.y + a.z + a.w; q0 = da; }
    else           { q1 = da; }
    float dc = c.x * c.x + c.y * c.y + c.z * c.z + c.w * c.w;
    if (lane < 16)      q1 += dc;
    else if (lane < 56) q2 = dc;

#pragma unroll
    for (int m = 1; m < 64; m <<= 1) {
        s0 += __shfl_xor(s0, m, 64);
        q0 += __shfl_xor(q0, m, 64);
        q1 += __shfl_xor(q1, m, 64);
        q2 += __shfl_xor(q2, m, 64);
    }

    int b = batch[node];
    const float* mrow = mod + (size_t)b * MODW;
    float4 m4 = *(const float4*)mrow;            // scales 0..2 (+unused col3)

    float mean = s0 * (1.0f / 128.0f);
    float var  = q0 * (1.0f / 128.0f) - mean * mean;
    float r0 = rsqrtf(var + EPS) * (1.0f + m4.x);
    float r1 = rsqrtf(q1 * (1.0f / 192.0f) + EPS) * (1.0f + m4.y);
    float r2 = rsqrtf(q2 * (1.0f / 160.0f) + EPS) * (1.0f + m4.z);

    float4* op = (float4*)(out + (size_t)node * 480);
    float4 o;
    if (lane < 32) {
        float4 sh = *(const float4*)(mrow + 4 + 4 * lane);   // shifts, 16B aligned
        o.x = (a.x - mean) * r0 + sh.x;
        o.y = (a.y - mean) * r0 + sh.y;
        o.z = (a.z - mean) * r0 + sh.z;
        o.w = (a.w - mean) * r0 + sh.w;
    } else {
        o.x = a.x * r1; o.y = a.y * r1; o.z = a.z * r1; o.w = a.w * r1;
    }
    op[lane] = o;
    if (lane < 56) {
        float rr = (lane < 16) ? r1 : r2;
        float4 o2;
        o2.x = c.x * rr; o2.y = c.y * rr; o2.z = c.z * rr; o2.w = c.w * rr;
        op[64 + lane] = o2;
    }
}

extern "C" void kernel_launch(void* const* d_in, const int* in_sizes, int n_in,
                              void* d_out, int out_size, void* d_ws, size_t ws_size,
                              hipStream_t stream) {
    const float* node_input = (const float*)d_in[0];
    const float* t          = (const float*)d_in[1];
    const int*   batch      = (const int*)d_in[2];
    const float* w1         = (const float*)d_in[3];
    const float* b1         = (const float*)d_in[4];
    const float* w2         = (const float*)d_in[5];
    const float* b2         = (const float*)d_in[6];
    const float* wm         = (const float*)d_in[7];
    const float* bm         = (const float*)d_in[8];
    float* out = (float*)d_out;

    int N = in_sizes[0] / 480;   // 100000
    int B = in_sizes[1];         // 1024

    float* ws = (float*)d_ws;
    float* h1 = ws;                        // B*512: silu(emb@w1+b1)
    float* h2 = h1 + (size_t)B * 512;      // B*512: silu(h1@w2+b2)  (silu folded)
    float* mb = h2 + (size_t)B * 512;      // B*132: compact mod

    // stage 1: emb (in-kernel trig) @ w1 + b1, silu
    k_stage<256, 512, 512, 512, true,  true,  false><<<dim3(B / 8, 8), 512, 0, stream>>>(
        nullptr, t, w1, b1, h1);
    // stage 2: h1 @ w2 + b2, trailing silu folded (next stage wants silu(t_emb))
    k_stage<512, 512, 512, 512, false, true,  false><<<dim3(B / 8, 8), 512, 0, stream>>>(
        h1, nullptr, w2, b2, h2);
    // stage 3: h2 @ wm + bm, only cols {0..3} U [224,352) -> compact 132-col rows
    k_stage<512, 352, MODW, MODW, false, false, true ><<<dim3(B / 8, 3), 512, 0, stream>>>(
        h2, nullptr, wm, bm, mb);

    k_main<<<(N + 3) / 4, 256, 0, stream>>>(node_input, batch, mb, out, N);
}